// Round 5
// baseline (813.165 us; speedup 1.0000x reference)
//
#include <hip/hip_runtime.h>

typedef __bf16 bf16;
typedef __bf16 bf16x4 __attribute__((ext_vector_type(4)));
typedef __bf16 bf16x8 __attribute__((ext_vector_type(8)));
typedef float floatx4 __attribute__((ext_vector_type(4)));

#define NB 4
#define NT 2048
#define NC 1024
#define NH 16

// ---------------- LayerNorm: one block per row of 1024 ----------------
// XBF: x is internal bf16 (else fp32 input). OUTF32: write fp32 (else bf16).
template <bool XBF, bool OUTF32>
__global__ void ln_kernel(const void* __restrict__ x, const float* __restrict__ g,
                          const float* __restrict__ b, void* __restrict__ y) {
  const int row = blockIdx.x;
  const int t = threadIdx.x;
  float f[4];
  if (XBF) {
    bf16x4 xv = *(const bf16x4*)((const bf16*)x + (size_t)row * NC + t * 4);
#pragma unroll
    for (int j = 0; j < 4; ++j) f[j] = (float)xv[j];
  } else {
    const float* xp = (const float*)x + (size_t)row * NC + t * 4;
#pragma unroll
    for (int j = 0; j < 4; ++j) f[j] = xp[j];
  }
  float s = 0.f, ss = 0.f;
#pragma unroll
  for (int j = 0; j < 4; ++j) { s += f[j]; ss += f[j] * f[j]; }
#pragma unroll
  for (int m = 32; m >= 1; m >>= 1) { s += __shfl_xor(s, m, 64); ss += __shfl_xor(ss, m, 64); }
  __shared__ float red[8];
  int wave = t >> 6, lane = t & 63;
  if (lane == 0) { red[wave * 2] = s; red[wave * 2 + 1] = ss; }
  __syncthreads();
  s = red[0] + red[2] + red[4] + red[6];
  ss = red[1] + red[3] + red[5] + red[7];
  float mean = s * (1.f / 1024.f);
  float var = ss * (1.f / 1024.f) - mean * mean;
  float rstd = rsqrtf(var + 1e-5f);
  const float* gp = g + t * 4;
  const float* bp = b + t * 4;
  if (OUTF32) {
    float* yp = (float*)y + (size_t)row * NC + t * 4;
#pragma unroll
    for (int j = 0; j < 4; ++j) yp[j] = (f[j] - mean) * rstd * gp[j] + bp[j];
  } else {
    bf16x4 ov;
#pragma unroll
    for (int j = 0; j < 4; ++j) ov[j] = (bf16)((f[j] - mean) * rstd * gp[j] + bp[j]);
    *(bf16x4*)((bf16*)y + (size_t)row * NC + t * 4) = ov;
  }
}

// ---------------- batched tiled transpose: fp32 in[b][r][c] -> bf16 out[b][c][r] ----------------
__global__ void transpose_f32(const float* __restrict__ in, bf16* __restrict__ out, int R, int C) {
  __shared__ __align__(16) bf16 tile[64][65];
  const int bz = blockIdx.z;
  const int r0 = blockIdx.y * 64, c0 = blockIdx.x * 64;
  const float* ip = in + (size_t)bz * R * C;
  bf16* op = out + (size_t)bz * R * C;
  const int t = threadIdx.x;
  const int tr = t >> 4, tc = (t & 15) * 4;
#pragma unroll
  for (int p = 0; p < 4; ++p) {
    int r = p * 16 + tr;
    const float* rp = ip + (size_t)(r0 + r) * C + c0 + tc;
#pragma unroll
    for (int j = 0; j < 4; ++j) tile[r][tc + j] = (bf16)rp[j];
  }
  __syncthreads();
#pragma unroll
  for (int p = 0; p < 4; ++p) {
    int c = p * 16 + tr;
#pragma unroll
    for (int j = 0; j < 4; ++j) op[(size_t)(c0 + c) * R + r0 + tc + j] = tile[tc + j][c];
  }
}

// ---------------- GEMM: A[M,K] @ Bt[N,K]^T, 128x128 tile, BK=32 ----------------
// AF32: A is fp32 (convert to bf16 at staging). bias always fp32.
// RES(+RESF32): residual bf16/fp32. OUTF32: fp32 store. QKV: scatter [B,H,T,HS] bf16.
template <bool AF32, bool BIAS, bool RES, bool RESF32, bool RELU, bool QKV, bool OUTF32>
__global__ void gemm_bt(const void* __restrict__ A, const bf16* __restrict__ Bt,
                        const float* __restrict__ bias, const void* __restrict__ res,
                        void* __restrict__ Cm, int M, int N, int K) {
  __shared__ __align__(16) bf16 As[128 * 32];
  __shared__ __align__(16) bf16 Bs[128 * 32];
  const int t = threadIdx.x;
  const int bn = blockIdx.x, bm = blockIdx.y;
  const int wave = t >> 6, lane = t & 63;
  const int wm = (wave >> 1) * 64, wn = (wave & 1) * 64;
  const int lm = lane & 15, quad = lane >> 4;
  const int lk = quad * 8;
  floatx4 acc[4][4];
#pragma unroll
  for (int mi = 0; mi < 4; ++mi)
#pragma unroll
    for (int ni = 0; ni < 4; ++ni) acc[mi][ni] = (floatx4){0.f, 0.f, 0.f, 0.f};

  const int srow = t >> 2, scol = (t & 3) << 3;
  for (int k0 = 0; k0 < K; k0 += 32) {
    bf16x8 av[2], bv[2];
#pragma unroll
    for (int j = 0; j < 2; ++j) {
      size_t arow = (size_t)(bm * 128 + srow + j * 64) * K + k0 + scol;
      size_t brow = (size_t)(bn * 128 + srow + j * 64) * K + k0 + scol;
      if (AF32) {
        const float* ap = (const float*)A + arow;
#pragma unroll
        for (int e = 0; e < 8; ++e) av[j][e] = (bf16)ap[e];
      } else {
        av[j] = *(const bf16x8*)((const bf16*)A + arow);
      }
      bv[j] = *(const bf16x8*)(Bt + brow);
    }
#pragma unroll
    for (int j = 0; j < 2; ++j) {
      int idx = (j * 64 + srow) * 4 + (t & 3);
      *(bf16x8*)(As + idx * 8) = av[j];
      *(bf16x8*)(Bs + idx * 8) = bv[j];
    }
    __syncthreads();
    bf16x8 a[4], b[4];
#pragma unroll
    for (int mi = 0; mi < 4; ++mi) a[mi] = *(const bf16x8*)(As + (wm + mi * 16 + lm) * 32 + lk);
#pragma unroll
    for (int ni = 0; ni < 4; ++ni) b[ni] = *(const bf16x8*)(Bs + (wn + ni * 16 + lm) * 32 + lk);
#pragma unroll
    for (int mi = 0; mi < 4; ++mi)
#pragma unroll
      for (int ni = 0; ni < 4; ++ni)
        acc[mi][ni] = __builtin_amdgcn_mfma_f32_16x16x32_bf16(a[mi], b[ni], acc[mi][ni], 0, 0, 0);
    __syncthreads();
  }
  // bias depends only on ni -> hoist
  float bvals[4] = {0.f, 0.f, 0.f, 0.f};
  if (BIAS) {
#pragma unroll
    for (int ni = 0; ni < 4; ++ni) bvals[ni] = bias[bn * 128 + wn + ni * 16 + lm];
  }
  // epilogue; C/D layout: col=lane&15, row=quad*4+reg (m89/m91-verified)
#pragma unroll
  for (int mi = 0; mi < 4; ++mi) {
#pragma unroll
    for (int r = 0; r < 4; ++r) {
      int row = bm * 128 + wm + mi * 16 + quad * 4 + r;
#pragma unroll
      for (int ni = 0; ni < 4; ++ni) {
        int col = bn * 128 + wn + ni * 16 + lm;
        float v = acc[mi][ni][r];
        if (BIAS) v += bvals[ni];
        if (RES) {
          if (RESF32) v += ((const float*)res)[(size_t)row * N + col];
          else v += (float)((const bf16*)res)[(size_t)row * N + col];
        }
        if (RELU) v = fmaxf(v, 0.f);
        if (QKV) {
          // row = b*2048+t, col = h*64+d  ->  [b][h][t][d]
          size_t addr = (((size_t)(row >> 11) * NH + (col >> 6)) * NT + (row & 2047)) * 64 + (col & 63);
          ((bf16*)Cm)[addr] = (bf16)v;
        } else if (OUTF32) {
          ((float*)Cm)[(size_t)row * N + col] = v;
        } else {
          ((bf16*)Cm)[(size_t)row * N + col] = (bf16)v;
        }
      }
    }
  }
}

// ---------------- flash attention: q,k,v [B*H][T][64] -> o [B][T][H*64] (bf16) ----------------
__global__ void flash_attn(const bf16* __restrict__ q, const bf16* __restrict__ k,
                           const bf16* __restrict__ v, bf16* __restrict__ o) {
  __shared__ __align__(16) bf16 Qs[128 * 64];
  __shared__ __align__(16) bf16 Ks[64 * 64];
  __shared__ __align__(16) bf16 Vts[64 * 64];  // [d][s]
  __shared__ __align__(16) bf16 Ps[128 * 64];
  const int t = threadIdx.x;
  const int bh = blockIdx.y, qt = blockIdx.x;
  const size_t bh_off = (size_t)bh * (NT * 64);
  const bf16* qp = q + bh_off + (size_t)qt * 128 * 64;
  const bf16* kp = k + bh_off;
  const bf16* vp = v + bh_off;
#pragma unroll
  for (int j = 0; j < 4; ++j) {
    int idx = j * 256 + t;
    *(bf16x8*)(Qs + idx * 8) = *(const bf16x8*)(qp + idx * 8);
  }
  const int wave = t >> 6, lane = t & 63;
  const int wm = wave * 32;
  const int lm = lane & 15, quad = lane >> 4;
  const int lk = quad * 8;
  floatx4 acc_o[2][4];
  float m_r[2][4], l_r[2][4];
#pragma unroll
  for (int mi = 0; mi < 2; ++mi)
#pragma unroll
    for (int ni = 0; ni < 4; ++ni) acc_o[mi][ni] = (floatx4){0.f, 0.f, 0.f, 0.f};
#pragma unroll
  for (int mi = 0; mi < 2; ++mi)
#pragma unroll
    for (int r = 0; r < 4; ++r) { m_r[mi][r] = -1e30f; l_r[mi][r] = 0.f; }

  for (int it = 0; it < NT / 64; ++it) {
    const bf16* kt = kp + (size_t)it * 64 * 64;
    const bf16* vt = vp + (size_t)it * 64 * 64;
#pragma unroll
    for (int j = 0; j < 2; ++j) {
      int idx = j * 256 + t;
      *(bf16x8*)(Ks + idx * 8) = *(const bf16x8*)(kt + idx * 8);
    }
    // V transpose stage: Vts[d][s] = V[s][d]
#pragma unroll
    for (int cc = 0; cc < 2; ++cc) {
      int c = 2 * t + cc;
      int s = c >> 3, d0 = (c & 7) << 3;
      bf16x8 vv = *(const bf16x8*)(vt + s * 64 + d0);
#pragma unroll
      for (int j = 0; j < 8; ++j) Vts[(d0 + j) * 64 + s] = vv[j];
    }
    __syncthreads();
    // S = Q @ K^T (scaled by 1/sqrt(C) = 1/32)
    floatx4 acc_s[2][4];
#pragma unroll
    for (int mi = 0; mi < 2; ++mi)
#pragma unroll
      for (int ni = 0; ni < 4; ++ni) acc_s[mi][ni] = (floatx4){0.f, 0.f, 0.f, 0.f};
#pragma unroll
    for (int kk = 0; kk < 2; ++kk) {
      bf16x8 a0 = *(const bf16x8*)(Qs + (wm + lm) * 64 + kk * 32 + lk);
      bf16x8 a1 = *(const bf16x8*)(Qs + (wm + 16 + lm) * 64 + kk * 32 + lk);
#pragma unroll
      for (int ni = 0; ni < 4; ++ni) {
        bf16x8 b = *(const bf16x8*)(Ks + (ni * 16 + lm) * 64 + kk * 32 + lk);
        acc_s[0][ni] = __builtin_amdgcn_mfma_f32_16x16x32_bf16(a0, b, acc_s[0][ni], 0, 0, 0);
        acc_s[1][ni] = __builtin_amdgcn_mfma_f32_16x16x32_bf16(a1, b, acc_s[1][ni], 0, 0, 0);
      }
    }
    // online softmax; row state replicated across each 16-lane group
#pragma unroll
    for (int mi = 0; mi < 2; ++mi) {
#pragma unroll
      for (int r = 0; r < 4; ++r) {
        float mx = m_r[mi][r];
#pragma unroll
        for (int ni = 0; ni < 4; ++ni) {
          float sv = acc_s[mi][ni][r] * 0.03125f;
          acc_s[mi][ni][r] = sv;
          mx = fmaxf(mx, sv);
        }
#pragma unroll
        for (int msk = 8; msk >= 1; msk >>= 1) mx = fmaxf(mx, __shfl_xor(mx, msk, 64));
        float alpha = __expf(m_r[mi][r] - mx);
        float rs = 0.f;
        int prow = wm + mi * 16 + quad * 4 + r;
#pragma unroll
        for (int ni = 0; ni < 4; ++ni) {
          float p = __expf(acc_s[mi][ni][r] - mx);
          rs += p;
          Ps[prow * 64 + ni * 16 + lm] = (bf16)p;
        }
#pragma unroll
        for (int msk = 8; msk >= 1; msk >>= 1) rs += __shfl_xor(rs, msk, 64);
        l_r[mi][r] = l_r[mi][r] * alpha + rs;
        m_r[mi][r] = mx;
#pragma unroll
        for (int ni = 0; ni < 4; ++ni) acc_o[mi][ni][r] *= alpha;
      }
    }
    __syncthreads();  // Ps visible
    // O += P @ V
#pragma unroll
    for (int kk = 0; kk < 2; ++kk) {
      bf16x8 a0 = *(const bf16x8*)(Ps + (wm + lm) * 64 + kk * 32 + lk);
      bf16x8 a1 = *(const bf16x8*)(Ps + (wm + 16 + lm) * 64 + kk * 32 + lk);
#pragma unroll
      for (int ni = 0; ni < 4; ++ni) {
        bf16x8 b = *(const bf16x8*)(Vts + (ni * 16 + lm) * 64 + kk * 32 + lk);
        acc_o[0][ni] = __builtin_amdgcn_mfma_f32_16x16x32_bf16(a0, b, acc_o[0][ni], 0, 0, 0);
        acc_o[1][ni] = __builtin_amdgcn_mfma_f32_16x16x32_bf16(a1, b, acc_o[1][ni], 0, 0, 0);
      }
    }
    __syncthreads();  // done with Ks/Vts before next stage
  }
  // epilogue: o[b][t][h*64+d]
  const int b = bh >> 4, h = bh & 15;
#pragma unroll
  for (int mi = 0; mi < 2; ++mi) {
#pragma unroll
    for (int r = 0; r < 4; ++r) {
      int trow = qt * 128 + wm + mi * 16 + quad * 4 + r;
      float inv = 1.f / l_r[mi][r];
#pragma unroll
      for (int ni = 0; ni < 4; ++ni) {
        int d = ni * 16 + lm;
        o[((size_t)b * NT + trow) * NC + h * 64 + d] = (bf16)(acc_o[mi][ni][r] * inv);
      }
    }
  }
}

extern "C" void kernel_launch(void* const* d_in, const int* in_sizes, int n_in,
                              void* d_out, int out_size, void* d_ws, size_t ws_size,
                              hipStream_t stream) {
  const float* x      = (const float*)d_in[0];
  const float* wq     = (const float*)d_in[1];
  const float* wk     = (const float*)d_in[2];
  const float* wv     = (const float*)d_in[3];
  const float* w_proj = (const float*)d_in[4];
  const float* b_proj = (const float*)d_in[5];
  const float* ln1_g  = (const float*)d_in[6];
  const float* ln1_b  = (const float*)d_in[7];
  const float* ln2_g  = (const float*)d_in[8];
  const float* ln2_b  = (const float*)d_in[9];
  const float* w1     = (const float*)d_in[10];
  const float* b1     = (const float*)d_in[11];
  const float* w2     = (const float*)d_in[12];
  const float* b2     = (const float*)d_in[13];

  // Workspace plan — 80 MB peak (proven-safe footprint); d_out (32 MB fp32) as scratch:
  //   [0,16)   x1 bf16 (LN1→proj residual); then W1T [0,8), W2T [8,16)
  //   [16,32)  qb (QKV→flash), then x2 (proj→LN2)
  //   [32,48)  kb   [48,64) vb
  //   [64,72)  WqT/WkT/WvT/WpT (2 MB each; dead after proj)
  //   hid = [16,80) bf16 (FF1→FF2)
  //   d_out: att bf16 (flash→proj), then x3 fp32 (LN2→FF1 A, FF2 residual), then final fp32 out
  char* w = (char*)d_ws;
  const size_t MB = 1024ull * 1024ull;
  bf16* x1  = (bf16*)(w + 0 * MB);
  bf16* W1T = (bf16*)(w + 0 * MB);
  bf16* W2T = (bf16*)(w + 8 * MB);
  bf16* qb  = (bf16*)(w + 16 * MB);
  bf16* x2  = (bf16*)(w + 16 * MB);
  bf16* hid = (bf16*)(w + 16 * MB);
  bf16* kb  = (bf16*)(w + 32 * MB);
  bf16* vb  = (bf16*)(w + 48 * MB);
  bf16* WqT = (bf16*)(w + 64 * MB);
  bf16* WkT = (bf16*)(w + 66 * MB);
  bf16* WvT = (bf16*)(w + 68 * MB);
  bf16* WpT = (bf16*)(w + 70 * MB);
  bf16*  att = (bf16*)d_out;   // scratch: bf16 att (first 16 MB of d_out)
  float* x3  = (float*)d_out;  // then fp32 x3 (full 32 MB), finally the fp32 output

  // repack weights to bf16 B^T [N,K]
  transpose_f32<<<dim3(1, 16, 16), 256, 0, stream>>>(wq, WqT, 1024, 64);  // [h][c][d]->[h*64+d][c]
  transpose_f32<<<dim3(1, 16, 16), 256, 0, stream>>>(wk, WkT, 1024, 64);
  transpose_f32<<<dim3(1, 16, 16), 256, 0, stream>>>(wv, WvT, 1024, 64);
  transpose_f32<<<dim3(16, 16, 1), 256, 0, stream>>>(w_proj, WpT, 1024, 1024);

  // x1 = LN1(x)  (fp32 in -> bf16 out)
  ln_kernel<false, false><<<8192, 256, 0, stream>>>(x, ln1_g, ln1_b, x1);
  // q,k,v = x1 @ Wq/k/v  (scatter [B,H,T,HS] bf16)
  gemm_bt<false, false, false, false, false, true, false><<<dim3(8, 64), 256, 0, stream>>>(x1, WqT, nullptr, nullptr, qb, 8192, 1024, 1024);
  gemm_bt<false, false, false, false, false, true, false><<<dim3(8, 64), 256, 0, stream>>>(x1, WkT, nullptr, nullptr, kb, 8192, 1024, 1024);
  gemm_bt<false, false, false, false, false, true, false><<<dim3(8, 64), 256, 0, stream>>>(x1, WvT, nullptr, nullptr, vb, 8192, 1024, 1024);
  // att(=d_out bf16) = attention(q,k,v), [B,T,C]
  flash_attn<<<dim3(16, 64), 256, 0, stream>>>(qb, kb, vb, att);
  // x2 = x1 + att @ w_proj + b_proj  (bf16 out; overlays dead qb)
  gemm_bt<false, true, true, false, false, false, false><<<dim3(8, 64), 256, 0, stream>>>(att, WpT, b_proj, x1, x2, 8192, 1024, 1024);
  // x3(=d_out fp32) = LN2(x2)  (att dead)
  ln_kernel<true, true><<<8192, 256, 0, stream>>>(x2, ln2_g, ln2_b, x3);
  // late weight repack into dead x1 region
  transpose_f32<<<dim3(64, 16, 1), 256, 0, stream>>>(w1, W1T, 1024, 4096);
  transpose_f32<<<dim3(16, 64, 1), 256, 0, stream>>>(w2, W2T, 4096, 1024);
  // hid = relu(x3 @ w1 + b1)  (A fp32->bf16 staging; hid overlays dead x2/kb/vb/W*T)
  gemm_bt<true, true, false, false, true, false, false><<<dim3(32, 64), 256, 0, stream>>>(x3, W1T, b1, nullptr, hid, 8192, 4096, 1024);
  // out = x3 + hid @ w2 + b2  (fp32 residual read + fp32 store, same-address in-thread RMW)
  gemm_bt<false, true, true, true, false, false, true><<<dim3(8, 64), 256, 0, stream>>>(hid, W2T, b2, x3, d_out, 8192, 1024, 4096);
}